// Round 7
// baseline (82.695 us; speedup 1.0000x reference)
//
#include <hip/hip_runtime.h>

// FingerprintPool: B=64, A=32, C=64, SEG_LENS=(1,167,512), F_fp=679.
// Math (R6-validated; biases cancel, max-subtraction dropped — decomposable):
//   ed_i[a] = exp(x[a]·w_inner_i); fe_i[a] = ed_i[a]·(x[a]·w_inter_i)
//   per column l (hit mask m): Z = sum_hit ed, u_l = exp((sum_hit fe)/Z), cf_l = u_l/Z
//   H_i[a] = sum_{l in seg i, hit(l,a)} cf_l ;  S_i = sum_{l in seg i} u_l
//   out[c] = sum_a x[a][c] * sum_i ed_i[a]*H_i[a]/S_i
//
// R7: single dispatch, grid 256 = 64 batches x 4 column-chunks (170 cols each).
// fp drain (the per-CU concurrency-bound ~3.5us) is split across 4 CUs.
// Producers (chunk 1..3) write H/S partials to ws via agent-scope atomic
// stores (write-through; no cross-XCD L2 staleness), then a sentinel flag
// (release, agent). Chunk-0 block spins (acquire, agent) and reduces.
// Sentinel scheme is initial-state independent; all 256 blocks co-resident.

constexpr int NB   = 64;
constexpr int NA   = 32;
constexpr int NC   = 64;
constexpr int NFP  = 679;
constexpr int S2   = 168;   // seg0 = {0}, seg1 = [1,168), seg2 = [168,680)
constexpr int CPB  = 4;     // chunks per batch
constexpr int CW   = 170;   // columns per chunk (4*170 = 680)
constexpr int WSTR = 128;   // ws floats per block: [0..95]=H, [96..98]=S, [127]=flag
constexpr unsigned SENT = 0x5EA50001u;

__device__ __forceinline__ int seg_of(int l) {
    return (l >= S2) ? 2 : ((l >= 1) ? 1 : 0);
}

__global__ __launch_bounds__(256) void fpool_kernel(
    const float* __restrict__ x,        // (2048, 64)
    const int*   __restrict__ fp,       // (2048, 679)
    const float* __restrict__ w_inner,  // (3, 64)
    const float* __restrict__ w_inter,  // (3, 64)
    float*       __restrict__ ws,       // (256, WSTR)
    float*       __restrict__ out)      // (64, 64)
{
    __shared__ float    x_s[NA][NC + 1];
    __shared__ float    w_s[6][NC];
    __shared__ float    ed_s[3][NA];
    __shared__ float    fe_s[3][NA];
    __shared__ unsigned mask_s[CW];
    __shared__ float    u_s[CW];
    __shared__ float    cf_s[CW];
    __shared__ float    part_s[8][96];   // sub-chunk H partials
    __shared__ float    pu_s[8][4];      // sub-chunk S partials
    __shared__ float    H_s[96];
    __shared__ float    S_s[3];
    __shared__ float    Gsum_s[NA];

    const int tid   = threadIdx.x;
    const int g     = blockIdx.x;
    const int b     = g >> 2;
    const int chunk = g & 3;
    const int l0    = chunk * CW;

    // ---- issue loads in first-use order: w, x, fp ----
    float wv0 = (tid < 192) ? w_inner[tid] : w_inter[tid - 192];
    float wv1 = 0.f;
    if (tid < 128) wv1 = w_inter[tid + 64];

    const float* xb = x + (size_t)b * NA * NC;
    float xv[8];
    #pragma unroll
    for (int k = 0; k < 8; ++k) xv[k] = xb[tid + k * 256];

    int v[NA];
    const bool haveCol = (tid < CW);
    const int  l       = l0 + tid;
    if (haveCol && l >= 1) {
        const int* f = fp + (size_t)b * NA * NFP + (l - 1);
        #pragma unroll
        for (int a = 0; a < NA; ++a) v[a] = f[(size_t)a * NFP];
    }

    ((float*)w_s)[tid] = wv0;
    if (tid < 128) ((float*)w_s)[tid + 256] = wv1;
    #pragma unroll
    for (int k = 0; k < 8; ++k) {
        const int idx = tid + k * 256;
        x_s[idx >> 6][idx & 63] = xv[k];
    }
    __syncthreads();

    // ---- phase 1: 96 dot-pairs -> ed, fe ----
    if (tid < 96) {
        const int i = tid >> 5, a = tid & 31;
        float dacc = 0.f, eacc = 0.f;
        #pragma unroll
        for (int c = 0; c < NC; ++c) {
            const float t = x_s[a][c];
            dacc += t * w_s[i][c];
            eacc += t * w_s[3 + i][c];
        }
        const float ed = __expf(dacc);
        ed_s[i][a] = ed;
        fe_s[i][a] = ed * eacc;
    }
    __syncthreads();

    // ---- phase 3: per-column mask, Z, u, cf ----
    if (haveCol) {
        unsigned m = 0xFFFFFFFFu;
        if (l >= 1) {
            m = 0u;
            #pragma unroll
            for (int a = 0; a < NA; ++a) m |= (v[a] != 0) ? (1u << a) : 0u;
        }
        const int i = seg_of(l);
        float Z = 0.f, P = 0.f;
        #pragma unroll
        for (int a = 0; a < NA; ++a) {
            const float bit = (float)((m >> a) & 1u);
            Z += bit * ed_s[i][a];
            P += bit * fe_s[i][a];
        }
        const float invZ = __frcp_rn(Z);
        const float u    = m ? __expf(P * invZ) : 0.f;
        mask_s[tid] = m;
        u_s[tid]    = u;
        cf_s[tid]   = m ? (u * invZ) : 0.f;
    }
    __syncthreads();

    // ---- phase 5: H/S partials over this chunk (8 sub-chunks of 22) ----
    {
        const int a = tid & 31, sub = tid >> 5;
        const int ts = sub * 22;
        const int te = (ts + 22 < CW) ? ts + 22 : CW;
        float h0 = 0.f, h1 = 0.f, h2 = 0.f, su = 0.f;
        for (int t = ts; t < te; ++t) {
            const float cf = cf_s[t] * (float)((mask_s[t] >> a) & 1u);
            const int   sg = seg_of(l0 + t);
            if (sg == 2)      h2 += cf;
            else if (sg == 1) h1 += cf;
            else              h0 += cf;
            if (a < 3 && sg == a) su += u_s[t];
        }
        part_s[sub][a]      = h0;
        part_s[sub][32 + a] = h1;
        part_s[sub][64 + a] = h2;
        if (a < 3) pu_s[sub][a] = su;
    }
    __syncthreads();

    // ---- phase 5b: reduce sub-chunks ----
    if (chunk != 0) {
        // producer: partials -> ws (agent-scope write-through), then flag
        float* wsb = ws + (size_t)g * WSTR;
        if (tid < 96) {
            float s = 0.f;
            #pragma unroll
            for (int c = 0; c < 8; ++c) s += part_s[c][tid];
            __hip_atomic_store(&wsb[tid], s, __ATOMIC_RELAXED, __HIP_MEMORY_SCOPE_AGENT);
        } else if (tid < 99) {
            const int i = tid - 96;
            float s = 0.f;
            #pragma unroll
            for (int c = 0; c < 8; ++c) s += pu_s[c][i];
            __hip_atomic_store(&wsb[tid], s, __ATOMIC_RELAXED, __HIP_MEMORY_SCOPE_AGENT);
        }
        __syncthreads();   // all stores complete (vmcnt drained) before flag
        if (tid == 0) {
            __hip_atomic_store((unsigned*)&wsb[WSTR - 1], SENT,
                               __ATOMIC_RELEASE, __HIP_MEMORY_SCOPE_AGENT);
        }
        return;
    }

    // reducer (chunk 0): own partials into LDS
    if (tid < 96) {
        float s = 0.f;
        #pragma unroll
        for (int c = 0; c < 8; ++c) s += part_s[c][tid];
        H_s[tid] = s;
    } else if (tid < 99) {
        const int i = tid - 96;
        float s = 0.f;
        #pragma unroll
        for (int c = 0; c < 8; ++c) s += pu_s[c][i];
        S_s[i] = s;
    }

    // spin on sibling flags (acquire, agent)
    if (tid < 3) {
        const unsigned* flag =
            (const unsigned*)(ws + (size_t)(g + 1 + tid) * WSTR) + (WSTR - 1);
        while (__hip_atomic_load(flag, __ATOMIC_ACQUIRE,
                                 __HIP_MEMORY_SCOPE_AGENT) != SENT) { }
    }
    __syncthreads();

    // fold sibling partials (agent-scope loads bypass stale caches)
    if (tid < 96) {
        float h = H_s[tid];
        #pragma unroll
        for (int k = 1; k < CPB; ++k)
            h += __hip_atomic_load(&ws[(size_t)(g + k) * WSTR + tid],
                                   __ATOMIC_RELAXED, __HIP_MEMORY_SCOPE_AGENT);
        H_s[tid] = h;
    } else if (tid < 99) {
        float s = S_s[tid - 96];
        #pragma unroll
        for (int k = 1; k < CPB; ++k)
            s += __hip_atomic_load(&ws[(size_t)(g + k) * WSTR + tid],
                                   __ATOMIC_RELAXED, __HIP_MEMORY_SCOPE_AGENT);
        S_s[tid - 96] = s;
    }
    __syncthreads();

    // ---- phase 6: Gsum then output ----
    if (tid < NA) {
        Gsum_s[tid] = ed_s[0][tid] * H_s[tid]      / S_s[0]
                    + ed_s[1][tid] * H_s[32 + tid] / S_s[1]
                    + ed_s[2][tid] * H_s[64 + tid] / S_s[2];
    }
    __syncthreads();
    if (tid < NC) {
        float acc = 0.f;
        #pragma unroll
        for (int a = 0; a < NA; ++a) acc += Gsum_s[a] * x_s[a][tid];
        out[b * NC + tid] = acc;
    }
}

extern "C" void kernel_launch(void* const* d_in, const int* in_sizes, int n_in,
                              void* d_out, int out_size, void* d_ws, size_t ws_size,
                              hipStream_t stream) {
    const float* x       = (const float*)d_in[0];
    // d_in[1] = batch (unused), d_in[3] = fp_length (unused)
    const int*   fp      = (const int*)d_in[2];
    const float* w_inner = (const float*)d_in[4];
    // d_in[5] = b_inner (cancels in softmax)
    const float* w_inter = (const float*)d_in[6];
    // d_in[7] = b_inter (cancels in softmax)
    float* out = (float*)d_out;
    float* ws  = (float*)d_ws;   // 256*128*4 = 128 KB of scratch

    fpool_kernel<<<NB * CPB, 256, 0, stream>>>(x, fp, w_inner, w_inter, ws, out);
}

// Round 8
// 78.796 us; speedup vs baseline: 1.0495x; 1.0495x over previous
//
#include <hip/hip_runtime.h>

// FingerprintPool: B=64, A=32, C=64, SEG_LENS=(1,167,512), F_fp=679.
// Math reduction (biases cancel; max-subtraction dropped — scores are O(1),
// validated exact-at-bf16 in R5/R6):
//   ed_i[a] = exp(x[a]·w_inner_i); fe_i[a] = ed_i[a]·(x[a]·w_inter_i)
//   per column l (hit mask m): Z = sum_hit ed, u_l = exp((sum_hit fe)/Z), cf_l = u_l/Z
//   H_i[a] = sum_{l in seg i, hit(l,a)} cf_l ;  S_i = sum_{l in seg i} u_l
//   out[c] = sum_a x[a][c] * sum_i ed_i[a]*H_i[a]/S_i
//
// R8 = revert to R6 (best: 78.2 µs). R4's 2-kernel split (+9 µs) and R7's
// cross-block sentinel reduction (+4.5 µs) both lost to coordination
// overhead; the controllable kernel slice is ~5 µs over a ~73 µs harness
// floor (ws poison fills at 80-83% HBM peak dominate every profile).

constexpr int NB   = 64;
constexpr int NA   = 32;
constexpr int NC   = 64;
constexpr int NFP  = 679;   // fp columns (without the implicit ones column)
constexpr int LTOT = 680;   // 1 + 167 + 512
constexpr int S2   = 168;   // seg2 start (seg0 = {0}, seg1 = [1,168))
constexpr int NT   = 1024;  // threads per block (16 waves)
constexpr int NCHK = 32;    // phase-5 chunks
constexpr int CHKW = 22;    // ceil(680/32): chunk 30 ends at 680, chunk 31 empty

__device__ __forceinline__ int seg_of(int l) {
    return (l >= S2) ? 2 : ((l >= 1) ? 1 : 0);
}

__global__ __launch_bounds__(NT) void fpool_kernel(
    const float* __restrict__ x,        // (2048, 64)
    const int*   __restrict__ fp,       // (2048, 679)
    const float* __restrict__ w_inner,  // (3, 64)
    const float* __restrict__ w_inter,  // (3, 64)
    float*       __restrict__ out)      // (64, 64)
{
    __shared__ float    x_s[NA][NC + 1];
    __shared__ float    w_s[6][NC];
    __shared__ float    ed_s[3][NA];
    __shared__ float    fe_s[3][NA];
    __shared__ unsigned mask_s[LTOT];
    __shared__ float    u_s[LTOT];
    __shared__ float    cf_s[LTOT];        // u_l / Z_l (0 for empty columns)
    __shared__ float    part_s[NCHK][96];  // H partials [chunk][i*32+a]
    __shared__ float    pu_s[NCHK][4];     // S partials [chunk][i]
    __shared__ float    H_s[96];
    __shared__ float    S_s[3];
    __shared__ float    Gsum_s[NA];

    const int tid = threadIdx.x;
    const int b   = blockIdx.x;
    const int l   = tid;

    // ---- issue loads in first-use order: w, x, fp ----
    float wv = 0.f;
    if (tid < 384) wv = (tid < 192) ? w_inner[tid] : w_inter[tid - 192];

    const float* xb = x + (size_t)b * NA * NC;
    const float  x0 = xb[tid];
    const float  x1 = xb[tid + NT];

    int v[NA];                              // fp row slice; mask built lazily
    if (l >= 1 && l < LTOT) {
        const int* f = fp + (size_t)b * NA * NFP + (l - 1);
        #pragma unroll
        for (int a = 0; a < NA; ++a) v[a] = f[(size_t)a * NFP];
    }

    if (tid < 384) ((float*)w_s)[tid] = wv;
    x_s[tid >> 6][tid & 63] = x0;
    { const int i1 = tid + NT; x_s[i1 >> 6][i1 & 63] = x1; }
    __syncthreads();

    // ---- phase 1: 96 dot-pairs -> ed, fe (no max-sub, no shuffles) ----
    if (tid < 96) {
        const int i = tid >> 5, a = tid & 31;
        float dacc = 0.f, eacc = 0.f;
        #pragma unroll
        for (int c = 0; c < NC; ++c) {
            const float t = x_s[a][c];
            dacc += t * w_s[i][c];
            eacc += t * w_s[3 + i][c];
        }
        const float ed = __expf(dacc);
        ed_s[i][a] = ed;
        fe_s[i][a] = ed * eacc;
    }
    __syncthreads();

    // ---- phase 3: per-column mask, Z, u, cf (fp regs drain here) ----
    if (l < LTOT) {
        unsigned m = 0xFFFFFFFFu;
        if (l >= 1) {
            m = 0u;
            #pragma unroll
            for (int a = 0; a < NA; ++a) m |= (v[a] != 0) ? (1u << a) : 0u;
        }
        const int i = seg_of(l);
        float Z = 0.f, P = 0.f;
        #pragma unroll
        for (int a = 0; a < NA; ++a) {
            const float bit = (float)((m >> a) & 1u);
            Z += bit * ed_s[i][a];
            P += bit * fe_s[i][a];
        }
        const float invZ = __frcp_rn(Z);              // Z>0 whenever m!=0
        const float u    = m ? __expf(P * invZ) : 0.f;
        mask_s[l] = m;
        u_s[l]    = u;
        cf_s[l]   = m ? (u * invZ) : 0.f;
    }
    __syncthreads();

    // ---- phase 5: H partials + S partials in one column scan ----
    {
        const int a = tid & 31, chunk = tid >> 5;
        const int ls = chunk * CHKW;
        const int le = (ls + CHKW < LTOT) ? ls + CHKW : LTOT;
        float h0 = 0.f, h1 = 0.f, h2 = 0.f, su = 0.f;
        for (int ll = ls; ll < le; ++ll) {
            const float cf = cf_s[ll] * (float)((mask_s[ll] >> a) & 1u);
            const int   sg = seg_of(ll);
            if (sg == 2)      h2 += cf;
            else if (sg == 1) h1 += cf;
            else              h0 += cf;
            if (a < 3 && sg == a) su += u_s[ll];      // lanes 0..2: S_i partial
        }
        part_s[chunk][a]      = h0;
        part_s[chunk][32 + a] = h1;
        part_s[chunk][64 + a] = h2;
        if (a < 3) pu_s[chunk][a] = su;
    }
    __syncthreads();

    // ---- phase 5b: reduce partials ----
    if (tid < 96) {
        float s = 0.f;
        #pragma unroll
        for (int c = 0; c < NCHK; ++c) s += part_s[c][tid];
        H_s[tid] = s;
    } else if (tid < 99) {
        const int i = tid - 96;
        float s = 0.f;
        #pragma unroll
        for (int c = 0; c < NCHK; ++c) s += pu_s[c][i];
        S_s[i] = s;
    }
    __syncthreads();

    // ---- phase 6: Gsum then output ----
    if (tid < NA) {
        Gsum_s[tid] = ed_s[0][tid] * H_s[tid]      / S_s[0]
                    + ed_s[1][tid] * H_s[32 + tid] / S_s[1]
                    + ed_s[2][tid] * H_s[64 + tid] / S_s[2];
    }
    __syncthreads();
    if (tid < NC) {
        float acc = 0.f;
        #pragma unroll
        for (int a = 0; a < NA; ++a) acc += Gsum_s[a] * x_s[a][tid];
        out[b * NC + tid] = acc;
    }
}

extern "C" void kernel_launch(void* const* d_in, const int* in_sizes, int n_in,
                              void* d_out, int out_size, void* d_ws, size_t ws_size,
                              hipStream_t stream) {
    const float* x       = (const float*)d_in[0];
    // d_in[1] = batch (unused), d_in[3] = fp_length (unused)
    const int*   fp      = (const int*)d_in[2];
    const float* w_inner = (const float*)d_in[4];
    // d_in[5] = b_inner (cancels in softmax)
    const float* w_inter = (const float*)d_in[6];
    // d_in[7] = b_inter (cancels in softmax)
    float* out = (float*)d_out;

    fpool_kernel<<<NB, NT, 0, stream>>>(x, fp, w_inner, w_inter, out);
}